// Round 17
// baseline (93.958 us; speedup 1.0000x reference)
//
#include <hip/hip_runtime.h>
#include <math.h>

typedef __attribute__((ext_vector_type(8))) short short8;
typedef __attribute__((ext_vector_type(4))) float f32x4;
typedef __attribute__((ext_vector_type(4))) unsigned short u16x4;

// Problem constants: B=2, L=2048, H=8, D=64, M=128.
constexpr int B_ = 2, L_ = 2048, H_ = 8, D_ = 64, M_ = 128;
constexpr int T_ = 64;            // chunk length
constexpr int C_ = L_ / T_;       // 32 chunks
constexpr float DN_ = 0.35355339059327373f;     // 64^-0.25
constexpr float RATIO_ = 0.08838834764831845f;  // 1/sqrt(128)
constexpr float EPSV_ = 1e-6f;
constexpr float REPS_ = RATIO_ * EPSV_;   // ratio*eps: k' additive floor
constexpr float KEPS_ = 64.0f * REPS_;    // per-chunk ks eps mass

__device__ inline unsigned short f2bf(float x) {  // RNE float->bf16
  const unsigned u = __float_as_uint(x);
  return (unsigned short)((u + 0x7fffu + ((u >> 16) & 1u)) >> 16);
}
__device__ inline float bf2f(unsigned short h) {
  return __uint_as_float(((unsigned)h) << 16);
}

// ---------------- feat: K-side only (unchanged from R16) ----------------
constexpr int FXK_ = 0, FPH_ = 4608, FVT_ = 13824;
constexpr int FKPT_ = 4608, FKVST_ = 4608;

__global__ __launch_bounds__(256, 4) void feat_kernel(
    const float* __restrict__ k, const float* __restrict__ P,
    const float* __restrict__ v, unsigned short* __restrict__ kvc16,
    float* __restrict__ ksc, unsigned short* __restrict__ vt16,
    float* __restrict__ blockmax, float* __restrict__ vsum) {
  __shared__ __align__(16) unsigned short sm[18432];
  __shared__ float diagk_s[T_];
  __shared__ float red4_s[4];

  const int sub = blockIdx.x;
  const int c = sub % C_, bh = sub / C_;
  const int b = bh >> 3, h = bh & 7;
  const int tid = threadIdx.x;
  const int w = tid >> 6, lane = tid & 63;
  const int l15 = lane & 15, l16 = lane >> 4;
  const int rblk = (w >> 1) * 32, cblk = (w & 1) * 64;

#pragma unroll
  for (int it = 0; it < 4; ++it) {
    const int i4 = tid + 256 * it;
    const int r = i4 >> 4, d0 = (i4 & 15) * 4;
    f32x4 t4 = *reinterpret_cast<const f32x4*>(
        &k[((size_t)(b * L_ + c * T_ + r) * H_ + h) * D_ + d0]);
    u16x4 hi;
    float sq = 0.f;
#pragma unroll
    for (int j = 0; j < 4; ++j) {
      const float xv = t4[j] * DN_;
      sq += xv * xv;
      hi[j] = f2bf(xv);
    }
    *reinterpret_cast<u16x4*>(&sm[FXK_ + r * 72 + d0]) = hi;
#pragma unroll
    for (int off = 1; off < 16; off <<= 1) sq += __shfl_xor(sq, off, 64);
    if ((tid & 15) == 0) diagk_s[r] = sq;
  }
  for (int i4 = tid; i4 < M_ * 16; i4 += 256) {
    const int m = i4 >> 4, d0 = (i4 & 15) * 4;
    const f32x4 t4 = *reinterpret_cast<const f32x4*>(&P[m * D_ + d0]);
    u16x4 hi;
#pragma unroll
    for (int j = 0; j < 4; ++j) hi[j] = f2bf(t4[j]);
    *reinterpret_cast<u16x4*>(&sm[FPH_ + m * 72 + d0]) = hi;
  }
#pragma unroll
  for (int it = 0; it < 4; ++it) {
    const int i4 = tid + 256 * it;
    const int t = i4 >> 4, d0 = (i4 & 15) * 4;
    const f32x4 t4 = *reinterpret_cast<const f32x4*>(
        &v[((size_t)(b * L_ + c * T_ + t) * H_ + h) * D_ + d0]);
#pragma unroll
    for (int j = 0; j < 4; ++j) sm[FVT_ + (d0 + j) * 72 + t] = f2bf(t4[j]);
  }
  __syncthreads();  // s1

  f32x4 acck[2][4];
#pragma unroll
  for (int i = 0; i < 2; ++i)
#pragma unroll
    for (int j = 0; j < 4; ++j) acck[i][j] = {0.f, 0.f, 0.f, 0.f};
#pragma unroll
  for (int kk = 0; kk < 2; ++kk) {
    short8 ah[2], bh8[4];
#pragma unroll
    for (int ti = 0; ti < 2; ++ti)
      ah[ti] = *reinterpret_cast<const short8*>(
          &sm[FXK_ + (rblk + ti * 16 + l15) * 72 + kk * 32 + l16 * 8]);
#pragma unroll
    for (int tj = 0; tj < 4; ++tj)
      bh8[tj] = *reinterpret_cast<const short8*>(
          &sm[FPH_ + (cblk + tj * 16 + l15) * 72 + kk * 32 + l16 * 8]);
#pragma unroll
    for (int ti = 0; ti < 2; ++ti)
#pragma unroll
      for (int tj = 0; tj < 4; ++tj)
        acck[ti][tj] = __builtin_amdgcn_mfma_f32_16x16x32_bf16(
            ah[ti], bh8[tj], acck[ti][tj], 0, 0, 0);
  }
  {
    float bm = -INFINITY;
#pragma unroll
    for (int ti = 0; ti < 2; ++ti)
#pragma unroll
      for (int tj = 0; tj < 4; ++tj)
#pragma unroll
        for (int j = 0; j < 4; ++j) bm = fmaxf(bm, acck[ti][tj][j]);
#pragma unroll
    for (int off = 1; off < 64; off <<= 1)
      bm = fmaxf(bm, __shfl_xor(bm, off, 64));
    if (lane == 0) red4_s[w] = bm;
  }
  __syncthreads();  // s2

  const float lmax =
      fmaxf(fmaxf(red4_s[0], red4_s[1]), fmaxf(red4_s[2], red4_s[3]));
  if (tid == 0) blockmax[sub] = lmax;
#pragma unroll
  for (int ti = 0; ti < 2; ++ti)
#pragma unroll
    for (int j = 0; j < 4; ++j) {
      const int row = rblk + ti * 16 + l16 * 4 + j;
      const float sub2 = 0.5f * diagk_s[row] + lmax;
#pragma unroll
      for (int tj = 0; tj < 4; ++tj) {
        const int col = cblk + tj * 16 + l15;
        sm[FKPT_ + col * 72 + row] = f2bf(RATIO_ * expf(acck[ti][tj][j] - sub2));
      }
    }
  __syncthreads();  // s3

  f32x4 acc2[2][4];
#pragma unroll
  for (int i = 0; i < 2; ++i)
#pragma unroll
    for (int j = 0; j < 4; ++j) acc2[i][j] = {0.f, 0.f, 0.f, 0.f};
#pragma unroll
  for (int kk = 0; kk < 2; ++kk) {
    short8 av[2], bv[4];
#pragma unroll
    for (int ti = 0; ti < 2; ++ti)
      av[ti] = *reinterpret_cast<const short8*>(
          &sm[FVT_ + (rblk + ti * 16 + l15) * 72 + kk * 32 + l16 * 8]);
#pragma unroll
    for (int tj = 0; tj < 4; ++tj)
      bv[tj] = *reinterpret_cast<const short8*>(
          &sm[FKPT_ + (cblk + tj * 16 + l15) * 72 + kk * 32 + l16 * 8]);
#pragma unroll
    for (int ti = 0; ti < 2; ++ti)
#pragma unroll
      for (int tj = 0; tj < 4; ++tj)
        acc2[ti][tj] = __builtin_amdgcn_mfma_f32_16x16x32_bf16(
            av[ti], bv[tj], acc2[ti][tj], 0, 0, 0);
  }
  {
    unsigned short* vg = vt16 + (size_t)(bh * C_ + c) * (D_ * T_);
    for (int i8 = tid; i8 < D_ * 8; i8 += 256) {
      const int d = i8 >> 3, t0 = (i8 & 7) * 8;
      *reinterpret_cast<short8*>(&vg[d * T_ + t0]) =
          *reinterpret_cast<const short8*>(&sm[FVT_ + d * 72 + t0]);
    }
  }
  if (tid < M_) {
    float s = 0.f;
#pragma unroll
    for (int t8 = 0; t8 < 8; ++t8) {
      const short8 h8 =
          *reinterpret_cast<const short8*>(&sm[FKPT_ + tid * 72 + t8 * 8]);
#pragma unroll
      for (int j = 0; j < 8; ++j) s += bf2f((unsigned short)h8[j]);
    }
    ksc[(size_t)(bh * C_ + c) * M_ + tid] = s;
  }
  if (tid >= 128 && tid < 128 + D_) {
    const int d = tid - 128;
    float s = 0.f;
#pragma unroll
    for (int t8 = 0; t8 < 8; ++t8) {
      const short8 h8 =
          *reinterpret_cast<const short8*>(&sm[FVT_ + d * 72 + t8 * 8]);
#pragma unroll
      for (int j = 0; j < 8; ++j) s += bf2f((unsigned short)h8[j]);
    }
    vsum[(size_t)(bh * C_ + c) * D_ + d] = s;
  }
  __syncthreads();  // s4
#pragma unroll
  for (int ti = 0; ti < 2; ++ti)
#pragma unroll
    for (int j = 0; j < 4; ++j) {
      const int row = rblk + ti * 16 + l16 * 4 + j;
#pragma unroll
      for (int tj = 0; tj < 4; ++tj) {
        const int col = cblk + tj * 16 + l15;
        sm[FKVST_ + row * 136 + col] = f2bf(acc2[ti][tj][j]);
      }
    }
  __syncthreads();  // s5
  {
    unsigned short* ob = kvc16 + (size_t)(bh * C_ + c) * (M_ * D_);
    for (int i8 = tid; i8 < D_ * 16; i8 += 256) {
      const int d = i8 >> 4, m0 = (i8 & 15) * 8;
      *reinterpret_cast<short8*>(&ob[d * M_ + m0]) =
          *reinterpret_cast<const short8*>(&sm[FKVST_ + d * 136 + m0]);
    }
  }
}

// ---------------- intra: recomputes feature maps AND the chunk prefix -----
// (prefix_kernel deleted, round-17: each block accumulates its own exclusive
// prefix over kvc/ksc/vsum from L2/L3 in the same fp32 order -> bit-identical
// bf16 operands; saves one launch + kvp16's 13MB HBM round trip.)
constexpr int IXQ_ = 0, IXK_ = 4608, IPH_ = 9216;
constexpr int IQP_ = 0, IKP_ = 9216, IS_ = 18432;

__global__ __launch_bounds__(256, 3) void intra_kernel(
    const float* __restrict__ q, const float* __restrict__ k,
    const float* __restrict__ P, const unsigned short* __restrict__ vt16,
    const unsigned short* __restrict__ kvc16, const float* __restrict__ ksc,
    const float* __restrict__ vsum, const float* __restrict__ blockmax,
    float* __restrict__ out) {
  __shared__ __align__(16) unsigned short sm[23040];
  __shared__ float diagq_s[T_];
  __shared__ float diagk_s[T_];
  __shared__ float wred_s[2][T_];
  __shared__ float qs2_s[2][T_];
  __shared__ float ksp_s[M_];
  __shared__ float denp_s[4][T_];
  __shared__ float den_s[T_];
  __shared__ float bm_s[C_];
  __shared__ float sc_s[C_];

  const int bid = blockIdx.x;
  const int c = bid % C_, bh = bid / C_;
  const int b = bh >> 3, h = bh & 7;
  const int tid = threadIdx.x;
  const int w = tid >> 6, lane = tid & 63;
  const int l15 = lane & 15, l16 = lane >> 4;
  const int rblk = (w >> 1) * 32;
  const int cblkF = (w & 1) * 64;
  const int cblkS = (w & 1) * 32;
  const int dblk = (w & 1) * 32;

  if (tid < C_) bm_s[tid] = blockmax[bh * C_ + tid];

  // ---- stage q, k (bf16 + diag) and P ----
#pragma unroll
  for (int it = 0; it < 4; ++it) {
    const int i4 = tid + 256 * it;
    const int r = i4 >> 4, d0 = (i4 & 15) * 4;
    f32x4 t4 = *reinterpret_cast<const f32x4*>(
        &q[((size_t)(b * L_ + c * T_ + r) * H_ + h) * D_ + d0]);
    u16x4 hi;
    float sq = 0.f;
#pragma unroll
    for (int j = 0; j < 4; ++j) {
      const float xv = t4[j] * DN_;
      sq += xv * xv;
      hi[j] = f2bf(xv);
    }
    *reinterpret_cast<u16x4*>(&sm[IXQ_ + r * 72 + d0]) = hi;
#pragma unroll
    for (int off = 1; off < 16; off <<= 1) sq += __shfl_xor(sq, off, 64);
    if ((tid & 15) == 0) diagq_s[r] = sq;
  }
#pragma unroll
  for (int it = 0; it < 4; ++it) {
    const int i4 = tid + 256 * it;
    const int r = i4 >> 4, d0 = (i4 & 15) * 4;
    f32x4 t4 = *reinterpret_cast<const f32x4*>(
        &k[((size_t)(b * L_ + c * T_ + r) * H_ + h) * D_ + d0]);
    u16x4 hi;
    float sq = 0.f;
#pragma unroll
    for (int j = 0; j < 4; ++j) {
      const float xv = t4[j] * DN_;
      sq += xv * xv;
      hi[j] = f2bf(xv);
    }
    *reinterpret_cast<u16x4*>(&sm[IXK_ + r * 72 + d0]) = hi;
#pragma unroll
    for (int off = 1; off < 16; off <<= 1) sq += __shfl_xor(sq, off, 64);
    if ((tid & 15) == 0) diagk_s[r] = sq;
  }
  for (int i4 = tid; i4 < M_ * 16; i4 += 256) {
    const int m = i4 >> 4, d0 = (i4 & 15) * 4;
    const f32x4 t4 = *reinterpret_cast<const f32x4*>(&P[m * D_ + d0]);
    u16x4 hi;
#pragma unroll
    for (int j = 0; j < 4; ++j) hi[j] = f2bf(t4[j]);
    *reinterpret_cast<u16x4*>(&sm[IPH_ + m * 72 + d0]) = hi;
  }
  __syncthreads();  // s1: staging + bm_s visible

  // sc_s (written before s2, read after s2)
  if (tid < C_) {
    float km = -INFINITY;
#pragma unroll
    for (int cc = 0; cc < C_; ++cc) km = fmaxf(km, bm_s[cc]);
    sc_s[tid] = expf(bm_s[tid] - km);
  }

  // ---- dash MFMAs ----
  f32x4 accq[2][4], acck[2][4];
#pragma unroll
  for (int i = 0; i < 2; ++i)
#pragma unroll
    for (int j = 0; j < 4; ++j) {
      accq[i][j] = {0.f, 0.f, 0.f, 0.f};
      acck[i][j] = {0.f, 0.f, 0.f, 0.f};
    }
#pragma unroll
  for (int kk = 0; kk < 2; ++kk) {
    short8 aq[2], ak[2], bh8[4];
#pragma unroll
    for (int ti = 0; ti < 2; ++ti) {
      aq[ti] = *reinterpret_cast<const short8*>(
          &sm[IXQ_ + (rblk + ti * 16 + l15) * 72 + kk * 32 + l16 * 8]);
      ak[ti] = *reinterpret_cast<const short8*>(
          &sm[IXK_ + (rblk + ti * 16 + l15) * 72 + kk * 32 + l16 * 8]);
    }
#pragma unroll
    for (int tj = 0; tj < 4; ++tj)
      bh8[tj] = *reinterpret_cast<const short8*>(
          &sm[IPH_ + (cblkF + tj * 16 + l15) * 72 + kk * 32 + l16 * 8]);
#pragma unroll
    for (int ti = 0; ti < 2; ++ti)
#pragma unroll
      for (int tj = 0; tj < 4; ++tj) {
        accq[ti][tj] = __builtin_amdgcn_mfma_f32_16x16x32_bf16(
            aq[ti], bh8[tj], accq[ti][tj], 0, 0, 0);
        acck[ti][tj] = __builtin_amdgcn_mfma_f32_16x16x32_bf16(
            ak[ti], bh8[tj], acck[ti][tj], 0, 0, 0);
      }
  }
  {  // Q per-row max
    float rmax[2][4];
#pragma unroll
    for (int ti = 0; ti < 2; ++ti)
#pragma unroll
      for (int j = 0; j < 4; ++j) {
        float m0 = fmaxf(fmaxf(accq[ti][0][j], accq[ti][1][j]),
                         fmaxf(accq[ti][2][j], accq[ti][3][j]));
#pragma unroll
        for (int off = 1; off < 16; off <<= 1)
          m0 = fmaxf(m0, __shfl_xor(m0, off, 64));
        rmax[ti][j] = m0;
      }
    if (l15 == 0) {
#pragma unroll
      for (int ti = 0; ti < 2; ++ti)
#pragma unroll
        for (int j = 0; j < 4; ++j)
          wred_s[w & 1][rblk + ti * 16 + l16 * 4 + j] = rmax[ti][j];
    }
  }
  __syncthreads();  // s2: wred + sc_s visible

  const float lmax = bm_s[c];
  // ---- epilogues: qp -> QP + qsum halves; kpE -> KP; ksp prefix ----
#pragma unroll
  for (int ti = 0; ti < 2; ++ti)
#pragma unroll
    for (int j = 0; j < 4; ++j) {
      const int row = rblk + ti * 16 + l16 * 4 + j;
      const float subq =
          0.5f * diagq_s[row] + fmaxf(wred_s[0][row], wred_s[1][row]);
      const float subk = 0.5f * diagk_s[row] + lmax;
      float qsp = 0.f;
#pragma unroll
      for (int tj = 0; tj < 4; ++tj) {
        const int col = cblkF + tj * 16 + l15;
        const float qv = RATIO_ * (expf(accq[ti][tj][j] - subq) + EPSV_);
        qsp += qv;
        sm[IQP_ + row * 136 + col] = f2bf(qv);
        sm[IKP_ + row * 136 + col] =
            f2bf(RATIO_ * expf(acck[ti][tj][j] - subk));
      }
#pragma unroll
      for (int off = 1; off < 16; off <<= 1) qsp += __shfl_xor(qsp, off, 64);
      if (l15 == 0) qs2_s[w & 1][row] = qsp;
    }
  if (tid < M_) {  // ksp prefix recompute (same order as old prefix_kernel)
    float s = 0.f;
    for (int cc = 0; cc < c; ++cc)
      s += ksc[(size_t)(bh * C_ + cc) * M_ + tid] * sc_s[cc] + KEPS_;
    ksp_s[tid] = s;
  }
  __syncthreads();  // s3: QP/KP/qs2/ksp visible

  // ---- prefetch V^T frags + recompute KVp prefix fragments ----
  const unsigned short* vg = vt16 + (size_t)(bh * C_ + c) * (D_ * T_);
  short8 vtr[2][2], kvr[4][2];
#pragma unroll
  for (int kk = 0; kk < 2; ++kk)
#pragma unroll
    for (int tj = 0; tj < 2; ++tj)
      vtr[kk][tj] = *reinterpret_cast<const short8*>(
          &vg[(dblk + tj * 16 + l15) * T_ + kk * 32 + l16 * 8]);
#pragma unroll
  for (int tj = 0; tj < 2; ++tj) {
    const int d = dblk + tj * 16 + l15;
    float acc8[4][8];
#pragma unroll
    for (int kk = 0; kk < 4; ++kk)
#pragma unroll
      for (int j = 0; j < 8; ++j) acc8[kk][j] = 0.f;
    for (int cc = 0; cc < c; ++cc) {
      const float scc = sc_s[cc];
      const float vse = REPS_ * vsum[(size_t)(bh * C_ + cc) * D_ + d];
      const unsigned short* kb =
          kvc16 + (size_t)(bh * C_ + cc) * (M_ * D_) + d * M_;
#pragma unroll
      for (int kk = 0; kk < 4; ++kk) {
        const short8 h8 =
            *reinterpret_cast<const short8*>(&kb[kk * 32 + l16 * 8]);
#pragma unroll
        for (int j = 0; j < 8; ++j)
          acc8[kk][j] += scc * bf2f((unsigned short)h8[j]) + vse;
      }
    }
#pragma unroll
    for (int kk = 0; kk < 4; ++kk) {
      short8 o;
#pragma unroll
      for (int j = 0; j < 8; ++j) o[j] = (short)f2bf(acc8[kk][j]);
      kvr[kk][tj] = o;
    }
  }

  const float sc = sc_s[c];

  // ---- S MFMA ----
  f32x4 Sacc[2][2];
#pragma unroll
  for (int i = 0; i < 2; ++i)
#pragma unroll
    for (int j = 0; j < 2; ++j) Sacc[i][j] = {0.f, 0.f, 0.f, 0.f};
#pragma unroll
  for (int kk = 0; kk < 4; ++kk) {
    short8 af[2], bf[2];
#pragma unroll
    for (int ti = 0; ti < 2; ++ti)
      af[ti] = *reinterpret_cast<const short8*>(
          &sm[IQP_ + (rblk + ti * 16 + l15) * 136 + kk * 32 + l16 * 8]);
#pragma unroll
    for (int tj = 0; tj < 2; ++tj)
      bf[tj] = *reinterpret_cast<const short8*>(
          &sm[IKP_ + (cblkS + tj * 16 + l15) * 136 + kk * 32 + l16 * 8]);
#pragma unroll
    for (int ti = 0; ti < 2; ++ti)
#pragma unroll
      for (int tj = 0; tj < 2; ++tj)
        Sacc[ti][tj] = __builtin_amdgcn_mfma_f32_16x16x32_bf16(
            af[ti], bf[tj], Sacc[ti][tj], 0, 0, 0);
  }
#pragma unroll
  for (int ti = 0; ti < 2; ++ti)
#pragma unroll
    for (int tj = 0; tj < 2; ++tj)
#pragma unroll
      for (int j = 0; j < 4; ++j) {
        const int row = rblk + ti * 16 + l16 * 4 + j;
        const int col = cblkS + tj * 16 + l15;
        const float add = REPS_ * (qs2_s[0][row] + qs2_s[1][row]);
        const float sv = (col <= row) ? Sacc[ti][tj][j] * sc + add : 0.f;
        sm[IS_ + row * 72 + col] = f2bf(sv);
      }
  __syncthreads();  // s4: S_s visible

  {  // den partials
    const int t = lane;
    float p = 0.f;
    if (w == 0) {
      for (int tp = 0; tp < 32; ++tp) p += bf2f(sm[IS_ + t * 72 + tp]);
    } else if (w == 1) {
      for (int tp = 32; tp < 64; ++tp) p += bf2f(sm[IS_ + t * 72 + tp]);
    } else if (w == 2) {
      for (int m = 0; m < 64; ++m)
        p += bf2f(sm[IQP_ + t * 136 + m]) * ksp_s[m];
    } else {
      for (int m = 64; m < 128; ++m)
        p += bf2f(sm[IQP_ + t * 136 + m]) * ksp_s[m];
    }
    denp_s[w][t] = p;
  }
  __syncthreads();  // s5
  if (tid < T_)
    den_s[tid] =
        denp_s[0][tid] + denp_s[1][tid] + denp_s[2][tid] + denp_s[3][tid];
  __syncthreads();  // s6

  // ---- PV: num = S@V^T + qp@KVp^T ----
  f32x4 Nacc[2][2];
#pragma unroll
  for (int i = 0; i < 2; ++i)
#pragma unroll
    for (int j = 0; j < 2; ++j) Nacc[i][j] = {0.f, 0.f, 0.f, 0.f};
#pragma unroll
  for (int kk = 0; kk < 2; ++kk) {
    short8 af[2];
#pragma unroll
    for (int ti = 0; ti < 2; ++ti)
      af[ti] = *reinterpret_cast<const short8*>(
          &sm[IS_ + (rblk + ti * 16 + l15) * 72 + kk * 32 + l16 * 8]);
#pragma unroll
    for (int ti = 0; ti < 2; ++ti)
#pragma unroll
      for (int tj = 0; tj < 2; ++tj)
        Nacc[ti][tj] = __builtin_amdgcn_mfma_f32_16x16x32_bf16(
            af[ti], vtr[kk][tj], Nacc[ti][tj], 0, 0, 0);
  }
#pragma unroll
  for (int kk = 0; kk < 4; ++kk) {
    short8 af[2];
#pragma unroll
    for (int ti = 0; ti < 2; ++ti)
      af[ti] = *reinterpret_cast<const short8*>(
          &sm[IQP_ + (rblk + ti * 16 + l15) * 136 + kk * 32 + l16 * 8]);
#pragma unroll
    for (int ti = 0; ti < 2; ++ti)
#pragma unroll
      for (int tj = 0; tj < 2; ++tj)
        Nacc[ti][tj] = __builtin_amdgcn_mfma_f32_16x16x32_bf16(
            af[ti], kvr[kk][tj], Nacc[ti][tj], 0, 0, 0);
  }

#pragma unroll
  for (int ti = 0; ti < 2; ++ti)
#pragma unroll
    for (int j = 0; j < 4; ++j) {
      const int row = rblk + ti * 16 + l16 * 4 + j;
      const float r = 1.f / den_s[row];
      float* orow = out + ((size_t)(b * L_ + c * T_ + row) * H_ + h) * D_;
#pragma unroll
      for (int tj = 0; tj < 2; ++tj) {
        const int col = dblk + tj * 16 + l15;
        orow[col] = Nacc[ti][tj][j] * r;
      }
    }
}

extern "C" void kernel_launch(void* const* d_in, const int* in_sizes, int n_in,
                              void* d_out, int out_size, void* d_ws,
                              size_t ws_size, hipStream_t stream) {
  const float* q = (const float*)d_in[0];
  const float* k = (const float*)d_in[1];
  const float* v = (const float*)d_in[2];
  const float* P = (const float*)d_in[3];
  float* out = (float*)d_out;

  // Workspace (~19 MB): blockmax | ksc | vsum | kvc16 | vt16
  float* ws = (float*)d_ws;
  float* blockmax = ws;                                   // 512
  float* ksc = blockmax + 512;                            // B*H*C*M
  float* vsum = ksc + (size_t)B_ * H_ * C_ * M_;          // B*H*C*D
  unsigned short* kvc16 = (unsigned short*)(vsum + (size_t)B_ * H_ * C_ * D_);
  unsigned short* vt16 = kvc16 + (size_t)B_ * H_ * C_ * D_ * M_;

  feat_kernel<<<B_ * H_ * C_, 256, 0, stream>>>(k, P, v, kvc16, ksc, vt16,
                                                blockmax, vsum);
  intra_kernel<<<B_ * H_ * C_, 256, 0, stream>>>(q, k, P, vt16, kvc16, ksc,
                                                 vsum, blockmax, out);
}

// Round 18
// 51.093 us; speedup vs baseline: 1.8390x; 1.8390x over previous
//
#include <hip/hip_runtime.h>
#include <math.h>

typedef __attribute__((ext_vector_type(8))) short short8;
typedef __attribute__((ext_vector_type(4))) float f32x4;
typedef __attribute__((ext_vector_type(4))) unsigned short u16x4;

// Problem constants: B=2, L=2048, H=8, D=64, M=128.
constexpr int B_ = 2, L_ = 2048, H_ = 8, D_ = 64, M_ = 128;
constexpr int T_ = 64;            // chunk length
constexpr int C_ = L_ / T_;       // 32 chunks
constexpr float DN_ = 0.35355339059327373f;     // 64^-0.25
constexpr float RATIO_ = 0.08838834764831845f;  // 1/sqrt(128)
constexpr float EPSV_ = 1e-6f;
constexpr float REPS_ = RATIO_ * EPSV_;   // ratio*eps: k' additive floor
constexpr float KEPS_ = 64.0f * REPS_;    // per-chunk ks eps mass

__device__ inline unsigned short f2bf(float x) {  // RNE float->bf16
  const unsigned u = __float_as_uint(x);
  return (unsigned short)((u + 0x7fffu + ((u >> 16) & 1u)) >> 16);
}
__device__ inline float bf2f(unsigned short h) {
  return __uint_as_float(((unsigned)h) << 16);
}

// ---------------- feat: K-side only (identical to R16) ----------------
constexpr int FXK_ = 0, FPH_ = 4608, FVT_ = 13824;
constexpr int FKPT_ = 4608, FKVST_ = 4608;

__global__ __launch_bounds__(256, 4) void feat_kernel(
    const float* __restrict__ k, const float* __restrict__ P,
    const float* __restrict__ v, unsigned short* __restrict__ kvc16,
    float* __restrict__ ksc, unsigned short* __restrict__ vt16,
    float* __restrict__ blockmax, float* __restrict__ vsum) {
  __shared__ __align__(16) unsigned short sm[18432];
  __shared__ float diagk_s[T_];
  __shared__ float red4_s[4];

  const int sub = blockIdx.x;
  const int c = sub % C_, bh = sub / C_;
  const int b = bh >> 3, h = bh & 7;
  const int tid = threadIdx.x;
  const int w = tid >> 6, lane = tid & 63;
  const int l15 = lane & 15, l16 = lane >> 4;
  const int rblk = (w >> 1) * 32, cblk = (w & 1) * 64;

#pragma unroll
  for (int it = 0; it < 4; ++it) {
    const int i4 = tid + 256 * it;
    const int r = i4 >> 4, d0 = (i4 & 15) * 4;
    f32x4 t4 = *reinterpret_cast<const f32x4*>(
        &k[((size_t)(b * L_ + c * T_ + r) * H_ + h) * D_ + d0]);
    u16x4 hi;
    float sq = 0.f;
#pragma unroll
    for (int j = 0; j < 4; ++j) {
      const float xv = t4[j] * DN_;
      sq += xv * xv;
      hi[j] = f2bf(xv);
    }
    *reinterpret_cast<u16x4*>(&sm[FXK_ + r * 72 + d0]) = hi;
#pragma unroll
    for (int off = 1; off < 16; off <<= 1) sq += __shfl_xor(sq, off, 64);
    if ((tid & 15) == 0) diagk_s[r] = sq;
  }
  for (int i4 = tid; i4 < M_ * 16; i4 += 256) {
    const int m = i4 >> 4, d0 = (i4 & 15) * 4;
    const f32x4 t4 = *reinterpret_cast<const f32x4*>(&P[m * D_ + d0]);
    u16x4 hi;
#pragma unroll
    for (int j = 0; j < 4; ++j) hi[j] = f2bf(t4[j]);
    *reinterpret_cast<u16x4*>(&sm[FPH_ + m * 72 + d0]) = hi;
  }
#pragma unroll
  for (int it = 0; it < 4; ++it) {
    const int i4 = tid + 256 * it;
    const int t = i4 >> 4, d0 = (i4 & 15) * 4;
    const f32x4 t4 = *reinterpret_cast<const f32x4*>(
        &v[((size_t)(b * L_ + c * T_ + t) * H_ + h) * D_ + d0]);
#pragma unroll
    for (int j = 0; j < 4; ++j) sm[FVT_ + (d0 + j) * 72 + t] = f2bf(t4[j]);
  }
  __syncthreads();  // s1

  f32x4 acck[2][4];
#pragma unroll
  for (int i = 0; i < 2; ++i)
#pragma unroll
    for (int j = 0; j < 4; ++j) acck[i][j] = {0.f, 0.f, 0.f, 0.f};
#pragma unroll
  for (int kk = 0; kk < 2; ++kk) {
    short8 ah[2], bh8[4];
#pragma unroll
    for (int ti = 0; ti < 2; ++ti)
      ah[ti] = *reinterpret_cast<const short8*>(
          &sm[FXK_ + (rblk + ti * 16 + l15) * 72 + kk * 32 + l16 * 8]);
#pragma unroll
    for (int tj = 0; tj < 4; ++tj)
      bh8[tj] = *reinterpret_cast<const short8*>(
          &sm[FPH_ + (cblk + tj * 16 + l15) * 72 + kk * 32 + l16 * 8]);
#pragma unroll
    for (int ti = 0; ti < 2; ++ti)
#pragma unroll
      for (int tj = 0; tj < 4; ++tj)
        acck[ti][tj] = __builtin_amdgcn_mfma_f32_16x16x32_bf16(
            ah[ti], bh8[tj], acck[ti][tj], 0, 0, 0);
  }
  {
    float bm = -INFINITY;
#pragma unroll
    for (int ti = 0; ti < 2; ++ti)
#pragma unroll
      for (int tj = 0; tj < 4; ++tj)
#pragma unroll
        for (int j = 0; j < 4; ++j) bm = fmaxf(bm, acck[ti][tj][j]);
#pragma unroll
    for (int off = 1; off < 64; off <<= 1)
      bm = fmaxf(bm, __shfl_xor(bm, off, 64));
    if (lane == 0) red4_s[w] = bm;
  }
  __syncthreads();  // s2

  const float lmax =
      fmaxf(fmaxf(red4_s[0], red4_s[1]), fmaxf(red4_s[2], red4_s[3]));
  if (tid == 0) blockmax[sub] = lmax;
#pragma unroll
  for (int ti = 0; ti < 2; ++ti)
#pragma unroll
    for (int j = 0; j < 4; ++j) {
      const int row = rblk + ti * 16 + l16 * 4 + j;
      const float sub2 = 0.5f * diagk_s[row] + lmax;
#pragma unroll
      for (int tj = 0; tj < 4; ++tj) {
        const int col = cblk + tj * 16 + l15;
        sm[FKPT_ + col * 72 + row] = f2bf(RATIO_ * expf(acck[ti][tj][j] - sub2));
      }
    }
  __syncthreads();  // s3

  f32x4 acc2[2][4];
#pragma unroll
  for (int i = 0; i < 2; ++i)
#pragma unroll
    for (int j = 0; j < 4; ++j) acc2[i][j] = {0.f, 0.f, 0.f, 0.f};
#pragma unroll
  for (int kk = 0; kk < 2; ++kk) {
    short8 av[2], bv[4];
#pragma unroll
    for (int ti = 0; ti < 2; ++ti)
      av[ti] = *reinterpret_cast<const short8*>(
          &sm[FVT_ + (rblk + ti * 16 + l15) * 72 + kk * 32 + l16 * 8]);
#pragma unroll
    for (int tj = 0; tj < 4; ++tj)
      bv[tj] = *reinterpret_cast<const short8*>(
          &sm[FKPT_ + (cblk + tj * 16 + l15) * 72 + kk * 32 + l16 * 8]);
#pragma unroll
    for (int ti = 0; ti < 2; ++ti)
#pragma unroll
      for (int tj = 0; tj < 4; ++tj)
        acc2[ti][tj] = __builtin_amdgcn_mfma_f32_16x16x32_bf16(
            av[ti], bv[tj], acc2[ti][tj], 0, 0, 0);
  }
  {
    unsigned short* vg = vt16 + (size_t)(bh * C_ + c) * (D_ * T_);
    for (int i8 = tid; i8 < D_ * 8; i8 += 256) {
      const int d = i8 >> 3, t0 = (i8 & 7) * 8;
      *reinterpret_cast<short8*>(&vg[d * T_ + t0]) =
          *reinterpret_cast<const short8*>(&sm[FVT_ + d * 72 + t0]);
    }
  }
  if (tid < M_) {
    float s = 0.f;
#pragma unroll
    for (int t8 = 0; t8 < 8; ++t8) {
      const short8 h8 =
          *reinterpret_cast<const short8*>(&sm[FKPT_ + tid * 72 + t8 * 8]);
#pragma unroll
      for (int j = 0; j < 8; ++j) s += bf2f((unsigned short)h8[j]);
    }
    ksc[(size_t)(bh * C_ + c) * M_ + tid] = s;
  }
  if (tid >= 128 && tid < 128 + D_) {
    const int d = tid - 128;
    float s = 0.f;
#pragma unroll
    for (int t8 = 0; t8 < 8; ++t8) {
      const short8 h8 =
          *reinterpret_cast<const short8*>(&sm[FVT_ + d * 72 + t8 * 8]);
#pragma unroll
      for (int j = 0; j < 8; ++j) s += bf2f((unsigned short)h8[j]);
    }
    vsum[(size_t)(bh * C_ + c) * D_ + d] = s;
  }
  __syncthreads();  // s4
#pragma unroll
  for (int ti = 0; ti < 2; ++ti)
#pragma unroll
    for (int j = 0; j < 4; ++j) {
      const int row = rblk + ti * 16 + l16 * 4 + j;
#pragma unroll
      for (int tj = 0; tj < 4; ++tj) {
        const int col = cblk + tj * 16 + l15;
        sm[FKVST_ + row * 136 + col] = f2bf(acc2[ti][tj][j]);
      }
    }
  __syncthreads();  // s5
  {
    unsigned short* ob = kvc16 + (size_t)(bh * C_ + c) * (M_ * D_);
    for (int i8 = tid; i8 < D_ * 16; i8 += 256) {
      const int d = i8 >> 4, m0 = (i8 & 15) * 8;
      *reinterpret_cast<short8*>(&ob[d * M_ + m0]) =
          *reinterpret_cast<const short8*>(&sm[FKVST_ + d * 136 + m0]);
    }
  }
}

// ---------------- prefix: identical to R16 ----------------
__global__ __launch_bounds__(256) void prefix_kernel(
    const unsigned short* __restrict__ kvc16,
    unsigned short* __restrict__ kvp16, float* __restrict__ ksc,
    const float* __restrict__ blockmax, const float* __restrict__ vsum) {
  __shared__ float bm_s[C_];
  __shared__ float sc_s[C_];
  __shared__ float vs_s[2][C_];
  const int bid = blockIdx.x;  // B*H*32
  const int ej = bid & 31, bh = bid >> 5;
  if (threadIdx.x < C_) bm_s[threadIdx.x] = blockmax[bh * C_ + threadIdx.x];
  if (threadIdx.x >= 64 && threadIdx.x < 64 + 2 * C_) {
    const int t = threadIdx.x - 64;
    const int ld = t >> 5, cc = t & 31;
    vs_s[ld][cc] = vsum[(size_t)(bh * C_ + cc) * D_ + ej * 2 + ld];
  }
  __syncthreads();
  if (threadIdx.x < C_) {
    float km = -INFINITY;
#pragma unroll
    for (int cc = 0; cc < C_; ++cc) km = fmaxf(km, bm_s[cc]);
    sc_s[threadIdx.x] = expf(bm_s[threadIdx.x] - km);
  }
  __syncthreads();
  const int e = ej * 256 + threadIdx.x;
  const int dl = threadIdx.x >> 7;
  float vals[C_];
#pragma unroll
  for (int cc = 0; cc < C_; ++cc)
    vals[cc] = bf2f(kvc16[(size_t)(bh * C_ + cc) * (M_ * D_) + e]) * sc_s[cc] +
               REPS_ * vs_s[dl][cc];
  float run = 0.f;
#pragma unroll
  for (int cc = 0; cc < C_; ++cc) {
    const float t = vals[cc];
    vals[cc] = run;
    run += t;
  }
#pragma unroll
  for (int cc = 0; cc < C_; ++cc)
    kvp16[(size_t)(bh * C_ + cc) * (M_ * D_) + e] = f2bf(vals[cc]);
  if (ej == 0 && threadIdx.x < M_) {
    const int m = threadIdx.x;
    float ks[C_];
#pragma unroll
    for (int cc = 0; cc < C_; ++cc)
      ks[cc] = ksc[(size_t)(bh * C_ + cc) * M_ + m] * sc_s[cc] + KEPS_;
    float rs = 0.f;
#pragma unroll
    for (int cc = 0; cc < C_; ++cc) {
      const float t = ks[cc];
      ks[cc] = rs;
      rs += t;
    }
#pragma unroll
    for (int cc = 0; cc < C_; ++cc)
      ksc[(size_t)(bh * C_ + cc) * M_ + m] = ks[cc];
  }
}

// ---------------- intra: R16 + S_s aliases KP (37KB -> 4 blk/CU) + top-of-
// kernel T14 prefetch of the once-used PV B-fragments ----------------
constexpr int IXQ_ = 0, IXK_ = 4608, IPH_ = 9216;
constexpr int IQP_ = 0, IKP_ = 9216;
constexpr int IS_ = 9216;  // aliases IKP (KP's last read = S MFMA; barrier'd)

__global__ __launch_bounds__(256, 4) void intra_kernel(
    const float* __restrict__ q, const float* __restrict__ k,
    const float* __restrict__ P, const unsigned short* __restrict__ vt16,
    const unsigned short* __restrict__ kvp16, const float* __restrict__ ksp,
    const float* __restrict__ blockmax, float* __restrict__ out) {
  __shared__ __align__(16) unsigned short sm[18432];  // 36.9 KB
  __shared__ float diagq_s[T_];
  __shared__ float diagk_s[T_];
  __shared__ float wred_s[2][T_];
  __shared__ float qs2_s[2][T_];
  __shared__ float ksp_s[M_];
  __shared__ float denp_s[4][T_];
  __shared__ float den_s[T_];
  __shared__ float bm_s[C_];

  const int bid = blockIdx.x;
  const int c = bid % C_, bh = bid / C_;
  const int b = bh >> 3, h = bh & 7;
  const int tid = threadIdx.x;
  const int w = tid >> 6, lane = tid & 63;
  const int l15 = lane & 15, l16 = lane >> 4;
  const int rblk = (w >> 1) * 32;
  const int cblkF = (w & 1) * 64;
  const int cblkS = (w & 1) * 32;
  const int dblk = (w & 1) * 32;

  // ---- T14: issue the 12 once-used PV B-fragment loads at kernel ENTRY ----
  const unsigned short* kvt = kvp16 + (size_t)(bh * C_ + c) * (M_ * D_);
  const unsigned short* vg = vt16 + (size_t)(bh * C_ + c) * (D_ * T_);
  short8 vtr[2][2], kvr[4][2];
#pragma unroll
  for (int kk = 0; kk < 2; ++kk)
#pragma unroll
    for (int tj = 0; tj < 2; ++tj)
      vtr[kk][tj] = *reinterpret_cast<const short8*>(
          &vg[(dblk + tj * 16 + l15) * T_ + kk * 32 + l16 * 8]);
#pragma unroll
  for (int kk = 0; kk < 4; ++kk)
#pragma unroll
    for (int tj = 0; tj < 2; ++tj)
      kvr[kk][tj] = *reinterpret_cast<const short8*>(
          &kvt[(dblk + tj * 16 + l15) * M_ + kk * 32 + l16 * 8]);

  if (tid < C_) bm_s[tid] = blockmax[bh * C_ + tid];
  if (tid < M_) ksp_s[tid] = ksp[(size_t)(bh * C_ + c) * M_ + tid];

  // ---- stage q, k (bf16 + diag) and P ----
#pragma unroll
  for (int it = 0; it < 4; ++it) {
    const int i4 = tid + 256 * it;
    const int r = i4 >> 4, d0 = (i4 & 15) * 4;
    f32x4 t4 = *reinterpret_cast<const f32x4*>(
        &q[((size_t)(b * L_ + c * T_ + r) * H_ + h) * D_ + d0]);
    u16x4 hi;
    float sq = 0.f;
#pragma unroll
    for (int j = 0; j < 4; ++j) {
      const float xv = t4[j] * DN_;
      sq += xv * xv;
      hi[j] = f2bf(xv);
    }
    *reinterpret_cast<u16x4*>(&sm[IXQ_ + r * 72 + d0]) = hi;
#pragma unroll
    for (int off = 1; off < 16; off <<= 1) sq += __shfl_xor(sq, off, 64);
    if ((tid & 15) == 0) diagq_s[r] = sq;
  }
#pragma unroll
  for (int it = 0; it < 4; ++it) {
    const int i4 = tid + 256 * it;
    const int r = i4 >> 4, d0 = (i4 & 15) * 4;
    f32x4 t4 = *reinterpret_cast<const f32x4*>(
        &k[((size_t)(b * L_ + c * T_ + r) * H_ + h) * D_ + d0]);
    u16x4 hi;
    float sq = 0.f;
#pragma unroll
    for (int j = 0; j < 4; ++j) {
      const float xv = t4[j] * DN_;
      sq += xv * xv;
      hi[j] = f2bf(xv);
    }
    *reinterpret_cast<u16x4*>(&sm[IXK_ + r * 72 + d0]) = hi;
#pragma unroll
    for (int off = 1; off < 16; off <<= 1) sq += __shfl_xor(sq, off, 64);
    if ((tid & 15) == 0) diagk_s[r] = sq;
  }
  for (int i4 = tid; i4 < M_ * 16; i4 += 256) {
    const int m = i4 >> 4, d0 = (i4 & 15) * 4;
    const f32x4 t4 = *reinterpret_cast<const f32x4*>(&P[m * D_ + d0]);
    u16x4 hi;
#pragma unroll
    for (int j = 0; j < 4; ++j) hi[j] = f2bf(t4[j]);
    *reinterpret_cast<u16x4*>(&sm[IPH_ + m * 72 + d0]) = hi;
  }
  __syncthreads();  // s1

  // ---- dash MFMAs ----
  f32x4 accq[2][4], acck[2][4];
#pragma unroll
  for (int i = 0; i < 2; ++i)
#pragma unroll
    for (int j = 0; j < 4; ++j) {
      accq[i][j] = {0.f, 0.f, 0.f, 0.f};
      acck[i][j] = {0.f, 0.f, 0.f, 0.f};
    }
#pragma unroll
  for (int kk = 0; kk < 2; ++kk) {
    short8 aq[2], ak[2], bh8[4];
#pragma unroll
    for (int ti = 0; ti < 2; ++ti) {
      aq[ti] = *reinterpret_cast<const short8*>(
          &sm[IXQ_ + (rblk + ti * 16 + l15) * 72 + kk * 32 + l16 * 8]);
      ak[ti] = *reinterpret_cast<const short8*>(
          &sm[IXK_ + (rblk + ti * 16 + l15) * 72 + kk * 32 + l16 * 8]);
    }
#pragma unroll
    for (int tj = 0; tj < 4; ++tj)
      bh8[tj] = *reinterpret_cast<const short8*>(
          &sm[IPH_ + (cblkF + tj * 16 + l15) * 72 + kk * 32 + l16 * 8]);
#pragma unroll
    for (int ti = 0; ti < 2; ++ti)
#pragma unroll
      for (int tj = 0; tj < 4; ++tj) {
        accq[ti][tj] = __builtin_amdgcn_mfma_f32_16x16x32_bf16(
            aq[ti], bh8[tj], accq[ti][tj], 0, 0, 0);
        acck[ti][tj] = __builtin_amdgcn_mfma_f32_16x16x32_bf16(
            ak[ti], bh8[tj], acck[ti][tj], 0, 0, 0);
      }
  }
  {  // Q per-row max
    float rmax[2][4];
#pragma unroll
    for (int ti = 0; ti < 2; ++ti)
#pragma unroll
      for (int j = 0; j < 4; ++j) {
        float m0 = fmaxf(fmaxf(accq[ti][0][j], accq[ti][1][j]),
                         fmaxf(accq[ti][2][j], accq[ti][3][j]));
#pragma unroll
        for (int off = 1; off < 16; off <<= 1)
          m0 = fmaxf(m0, __shfl_xor(m0, off, 64));
        rmax[ti][j] = m0;
      }
    if (l15 == 0) {
#pragma unroll
      for (int ti = 0; ti < 2; ++ti)
#pragma unroll
        for (int j = 0; j < 4; ++j)
          wred_s[w & 1][rblk + ti * 16 + l16 * 4 + j] = rmax[ti][j];
    }
  }
  __syncthreads();  // s2: wred visible; dash reads of XQ/XK/PH done

  const float lmax = bm_s[c];  // same units as feat's kpE
  // ---- epilogues: qp -> QP + qsum halves; kpE -> KP (over PH) ----
#pragma unroll
  for (int ti = 0; ti < 2; ++ti)
#pragma unroll
    for (int j = 0; j < 4; ++j) {
      const int row = rblk + ti * 16 + l16 * 4 + j;
      const float subq =
          0.5f * diagq_s[row] + fmaxf(wred_s[0][row], wred_s[1][row]);
      const float subk = 0.5f * diagk_s[row] + lmax;
      float qsp = 0.f;
#pragma unroll
      for (int tj = 0; tj < 4; ++tj) {
        const int col = cblkF + tj * 16 + l15;
        const float qv = RATIO_ * (expf(accq[ti][tj][j] - subq) + EPSV_);
        qsp += qv;
        sm[IQP_ + row * 136 + col] = f2bf(qv);
        sm[IKP_ + row * 136 + col] =
            f2bf(RATIO_ * expf(acck[ti][tj][j] - subk));
      }
#pragma unroll
      for (int off = 1; off < 16; off <<= 1) qsp += __shfl_xor(qsp, off, 64);
      if (l15 == 0) qs2_s[w & 1][row] = qsp;
    }
  __syncthreads();  // s3: QP/KP/qs2 visible

  float km = -INFINITY;
#pragma unroll
  for (int cc = 0; cc < C_; ++cc) km = fmaxf(km, bm_s[cc]);
  const float sc = expf(bm_s[c] - km);

  // ---- S MFMA (reads QP + KP) ----
  f32x4 Sacc[2][2];
#pragma unroll
  for (int i = 0; i < 2; ++i)
#pragma unroll
    for (int j = 0; j < 2; ++j) Sacc[i][j] = {0.f, 0.f, 0.f, 0.f};
#pragma unroll
  for (int kk = 0; kk < 4; ++kk) {
    short8 af[2], bf[2];
#pragma unroll
    for (int ti = 0; ti < 2; ++ti)
      af[ti] = *reinterpret_cast<const short8*>(
          &sm[IQP_ + (rblk + ti * 16 + l15) * 136 + kk * 32 + l16 * 8]);
#pragma unroll
    for (int tj = 0; tj < 2; ++tj)
      bf[tj] = *reinterpret_cast<const short8*>(
          &sm[IKP_ + (cblkS + tj * 16 + l15) * 136 + kk * 32 + l16 * 8]);
#pragma unroll
    for (int ti = 0; ti < 2; ++ti)
#pragma unroll
      for (int tj = 0; tj < 2; ++tj)
        Sacc[ti][tj] = __builtin_amdgcn_mfma_f32_16x16x32_bf16(
            af[ti], bf[tj], Sacc[ti][tj], 0, 0, 0);
  }
  __syncthreads();  // s3b: ALL waves' KP reads done -> S_s may alias KP

#pragma unroll
  for (int ti = 0; ti < 2; ++ti)
#pragma unroll
    for (int tj = 0; tj < 2; ++tj)
#pragma unroll
      for (int j = 0; j < 4; ++j) {
        const int row = rblk + ti * 16 + l16 * 4 + j;
        const int col = cblkS + tj * 16 + l15;
        const float add = REPS_ * (qs2_s[0][row] + qs2_s[1][row]);
        const float sv = (col <= row) ? Sacc[ti][tj][j] * sc + add : 0.f;
        sm[IS_ + row * 72 + col] = f2bf(sv);
      }
  __syncthreads();  // s4: S_s visible

  {  // den partials
    const int t = lane;
    float p = 0.f;
    if (w == 0) {
      for (int tp = 0; tp < 32; ++tp) p += bf2f(sm[IS_ + t * 72 + tp]);
    } else if (w == 1) {
      for (int tp = 32; tp < 64; ++tp) p += bf2f(sm[IS_ + t * 72 + tp]);
    } else if (w == 2) {
      for (int m = 0; m < 64; ++m)
        p += bf2f(sm[IQP_ + t * 136 + m]) * ksp_s[m];
    } else {
      for (int m = 64; m < 128; ++m)
        p += bf2f(sm[IQP_ + t * 136 + m]) * ksp_s[m];
    }
    denp_s[w][t] = p;
  }
  __syncthreads();  // s5
  if (tid < T_)
    den_s[tid] =
        denp_s[0][tid] + denp_s[1][tid] + denp_s[2][tid] + denp_s[3][tid];
  __syncthreads();  // s6

  // ---- PV: num = S@V^T + qp@KVp^T (B frags prefetched at entry) ----
  f32x4 Nacc[2][2];
#pragma unroll
  for (int i = 0; i < 2; ++i)
#pragma unroll
    for (int j = 0; j < 2; ++j) Nacc[i][j] = {0.f, 0.f, 0.f, 0.f};
#pragma unroll
  for (int kk = 0; kk < 2; ++kk) {
    short8 af[2];
#pragma unroll
    for (int ti = 0; ti < 2; ++ti)
      af[ti] = *reinterpret_cast<const short8*>(
          &sm[IS_ + (rblk + ti * 16 + l15) * 72 + kk * 32 + l16 * 8]);
#pragma unroll
    for (int ti = 0; ti < 2; ++ti)
#pragma unroll
      for (int tj = 0; tj < 2; ++tj)
        Nacc[ti][tj] = __builtin_amdgcn_mfma_f32_16x16x32_bf16(
            af[ti], vtr[kk][tj], Nacc[ti][tj], 0, 0, 0);
  }
#pragma unroll
  for (int kk = 0; kk < 4; ++kk) {
    short8 af[2];
#pragma unroll
    for (int ti = 0; ti < 2; ++ti)
      af[ti] = *reinterpret_cast<const short8*>(
          &sm[IQP_ + (rblk + ti * 16 + l15) * 136 + kk * 32 + l16 * 8]);
#pragma unroll
    for (int ti = 0; ti < 2; ++ti)
#pragma unroll
      for (int tj = 0; tj < 2; ++tj)
        Nacc[ti][tj] = __builtin_amdgcn_mfma_f32_16x16x32_bf16(
            af[ti], kvr[kk][tj], Nacc[ti][tj], 0, 0, 0);
  }

#pragma unroll
  for (int ti = 0; ti < 2; ++ti)
#pragma unroll
    for (int j = 0; j < 4; ++j) {
      const int row = rblk + ti * 16 + l16 * 4 + j;
      const float r = 1.f / den_s[row];
      float* orow = out + ((size_t)(b * L_ + c * T_ + row) * H_ + h) * D_;
#pragma unroll
      for (int tj = 0; tj < 2; ++tj) {
        const int col = dblk + tj * 16 + l15;
        orow[col] = Nacc[ti][tj][j] * r;
      }
    }
}

extern "C" void kernel_launch(void* const* d_in, const int* in_sizes, int n_in,
                              void* d_out, int out_size, void* d_ws,
                              size_t ws_size, hipStream_t stream) {
  const float* q = (const float*)d_in[0];
  const float* k = (const float*)d_in[1];
  const float* v = (const float*)d_in[2];
  const float* P = (const float*)d_in[3];
  float* out = (float*)d_out;

  // Workspace (~26 MB): blockmax | ksc | vsum | kvc16 | kvp16 | vt16
  float* ws = (float*)d_ws;
  float* blockmax = ws;                                   // 512
  float* ksc = blockmax + 512;                            // B*H*C*M
  float* vsum = ksc + (size_t)B_ * H_ * C_ * M_;          // B*H*C*D
  unsigned short* kvc16 = (unsigned short*)(vsum + (size_t)B_ * H_ * C_ * D_);
  unsigned short* kvp16 = kvc16 + (size_t)B_ * H_ * C_ * D_ * M_;
  unsigned short* vt16 = kvp16 + (size_t)B_ * H_ * C_ * D_ * M_;

  feat_kernel<<<B_ * H_ * C_, 256, 0, stream>>>(k, P, v, kvc16, ksc, vt16,
                                                blockmax, vsum);
  prefix_kernel<<<B_ * H_ * 32, 256, 0, stream>>>(kvc16, kvp16, ksc, blockmax,
                                                  vsum);
  intra_kernel<<<B_ * H_ * C_, 256, 0, stream>>>(q, k, P, vt16, kvp16, ksc,
                                                 blockmax, out);
}

// Round 19
// 42.323 us; speedup vs baseline: 2.2200x; 1.2072x over previous
//
#include <hip/hip_runtime.h>
#include <math.h>

typedef __attribute__((ext_vector_type(8))) short short8;
typedef __attribute__((ext_vector_type(4))) float f32x4;
typedef __attribute__((ext_vector_type(4))) unsigned short u16x4;

// Problem constants: B=2, L=2048, H=8, D=64, M=128.
constexpr int B_ = 2, L_ = 2048, H_ = 8, D_ = 64, M_ = 128;
constexpr int T_ = 64;            // chunk length
constexpr int C_ = L_ / T_;       // 32 chunks
constexpr float DN_ = 0.35355339059327373f;     // 64^-0.25
constexpr float RATIO_ = 0.08838834764831845f;  // 1/sqrt(128)
constexpr float EPSV_ = 1e-6f;
constexpr float REPS_ = RATIO_ * EPSV_;   // ratio*eps: k' additive floor
constexpr float KEPS_ = 64.0f * REPS_;    // per-chunk ks eps mass

__device__ inline unsigned short f2bf(float x) {  // RNE float->bf16
  const unsigned u = __float_as_uint(x);
  return (unsigned short)((u + 0x7fffu + ((u >> 16) & 1u)) >> 16);
}
__device__ inline float bf2f(unsigned short h) {
  return __uint_as_float(((unsigned)h) << 16);
}

// ---------------- feat: K-side only (identical to R16) ----------------
constexpr int FXK_ = 0, FPH_ = 4608, FVT_ = 13824;
constexpr int FKPT_ = 4608, FKVST_ = 4608;

__global__ __launch_bounds__(256, 4) void feat_kernel(
    const float* __restrict__ k, const float* __restrict__ P,
    const float* __restrict__ v, unsigned short* __restrict__ kvc16,
    float* __restrict__ ksc, unsigned short* __restrict__ vt16,
    float* __restrict__ blockmax, float* __restrict__ vsum) {
  __shared__ __align__(16) unsigned short sm[18432];
  __shared__ float diagk_s[T_];
  __shared__ float red4_s[4];

  const int sub = blockIdx.x;
  const int c = sub % C_, bh = sub / C_;
  const int b = bh >> 3, h = bh & 7;
  const int tid = threadIdx.x;
  const int w = tid >> 6, lane = tid & 63;
  const int l15 = lane & 15, l16 = lane >> 4;
  const int rblk = (w >> 1) * 32, cblk = (w & 1) * 64;

#pragma unroll
  for (int it = 0; it < 4; ++it) {
    const int i4 = tid + 256 * it;
    const int r = i4 >> 4, d0 = (i4 & 15) * 4;
    f32x4 t4 = *reinterpret_cast<const f32x4*>(
        &k[((size_t)(b * L_ + c * T_ + r) * H_ + h) * D_ + d0]);
    u16x4 hi;
    float sq = 0.f;
#pragma unroll
    for (int j = 0; j < 4; ++j) {
      const float xv = t4[j] * DN_;
      sq += xv * xv;
      hi[j] = f2bf(xv);
    }
    *reinterpret_cast<u16x4*>(&sm[FXK_ + r * 72 + d0]) = hi;
#pragma unroll
    for (int off = 1; off < 16; off <<= 1) sq += __shfl_xor(sq, off, 64);
    if ((tid & 15) == 0) diagk_s[r] = sq;
  }
  for (int i4 = tid; i4 < M_ * 16; i4 += 256) {
    const int m = i4 >> 4, d0 = (i4 & 15) * 4;
    const f32x4 t4 = *reinterpret_cast<const f32x4*>(&P[m * D_ + d0]);
    u16x4 hi;
#pragma unroll
    for (int j = 0; j < 4; ++j) hi[j] = f2bf(t4[j]);
    *reinterpret_cast<u16x4*>(&sm[FPH_ + m * 72 + d0]) = hi;
  }
#pragma unroll
  for (int it = 0; it < 4; ++it) {
    const int i4 = tid + 256 * it;
    const int t = i4 >> 4, d0 = (i4 & 15) * 4;
    const f32x4 t4 = *reinterpret_cast<const f32x4*>(
        &v[((size_t)(b * L_ + c * T_ + t) * H_ + h) * D_ + d0]);
#pragma unroll
    for (int j = 0; j < 4; ++j) sm[FVT_ + (d0 + j) * 72 + t] = f2bf(t4[j]);
  }
  __syncthreads();  // s1

  f32x4 acck[2][4];
#pragma unroll
  for (int i = 0; i < 2; ++i)
#pragma unroll
    for (int j = 0; j < 4; ++j) acck[i][j] = {0.f, 0.f, 0.f, 0.f};
#pragma unroll
  for (int kk = 0; kk < 2; ++kk) {
    short8 ah[2], bh8[4];
#pragma unroll
    for (int ti = 0; ti < 2; ++ti)
      ah[ti] = *reinterpret_cast<const short8*>(
          &sm[FXK_ + (rblk + ti * 16 + l15) * 72 + kk * 32 + l16 * 8]);
#pragma unroll
    for (int tj = 0; tj < 4; ++tj)
      bh8[tj] = *reinterpret_cast<const short8*>(
          &sm[FPH_ + (cblk + tj * 16 + l15) * 72 + kk * 32 + l16 * 8]);
#pragma unroll
    for (int ti = 0; ti < 2; ++ti)
#pragma unroll
      for (int tj = 0; tj < 4; ++tj)
        acck[ti][tj] = __builtin_amdgcn_mfma_f32_16x16x32_bf16(
            ah[ti], bh8[tj], acck[ti][tj], 0, 0, 0);
  }
  {
    float bm = -INFINITY;
#pragma unroll
    for (int ti = 0; ti < 2; ++ti)
#pragma unroll
      for (int tj = 0; tj < 4; ++tj)
#pragma unroll
        for (int j = 0; j < 4; ++j) bm = fmaxf(bm, acck[ti][tj][j]);
#pragma unroll
    for (int off = 1; off < 64; off <<= 1)
      bm = fmaxf(bm, __shfl_xor(bm, off, 64));
    if (lane == 0) red4_s[w] = bm;
  }
  __syncthreads();  // s2

  const float lmax =
      fmaxf(fmaxf(red4_s[0], red4_s[1]), fmaxf(red4_s[2], red4_s[3]));
  if (tid == 0) blockmax[sub] = lmax;
#pragma unroll
  for (int ti = 0; ti < 2; ++ti)
#pragma unroll
    for (int j = 0; j < 4; ++j) {
      const int row = rblk + ti * 16 + l16 * 4 + j;
      const float sub2 = 0.5f * diagk_s[row] + lmax;
#pragma unroll
      for (int tj = 0; tj < 4; ++tj) {
        const int col = cblk + tj * 16 + l15;
        sm[FKPT_ + col * 72 + row] = f2bf(RATIO_ * expf(acck[ti][tj][j] - sub2));
      }
    }
  __syncthreads();  // s3

  f32x4 acc2[2][4];
#pragma unroll
  for (int i = 0; i < 2; ++i)
#pragma unroll
    for (int j = 0; j < 4; ++j) acc2[i][j] = {0.f, 0.f, 0.f, 0.f};
#pragma unroll
  for (int kk = 0; kk < 2; ++kk) {
    short8 av[2], bv[4];
#pragma unroll
    for (int ti = 0; ti < 2; ++ti)
      av[ti] = *reinterpret_cast<const short8*>(
          &sm[FVT_ + (rblk + ti * 16 + l15) * 72 + kk * 32 + l16 * 8]);
#pragma unroll
    for (int tj = 0; tj < 4; ++tj)
      bv[tj] = *reinterpret_cast<const short8*>(
          &sm[FKPT_ + (cblk + tj * 16 + l15) * 72 + kk * 32 + l16 * 8]);
#pragma unroll
    for (int ti = 0; ti < 2; ++ti)
#pragma unroll
      for (int tj = 0; tj < 4; ++tj)
        acc2[ti][tj] = __builtin_amdgcn_mfma_f32_16x16x32_bf16(
            av[ti], bv[tj], acc2[ti][tj], 0, 0, 0);
  }
  {
    unsigned short* vg = vt16 + (size_t)(bh * C_ + c) * (D_ * T_);
    for (int i8 = tid; i8 < D_ * 8; i8 += 256) {
      const int d = i8 >> 3, t0 = (i8 & 7) * 8;
      *reinterpret_cast<short8*>(&vg[d * T_ + t0]) =
          *reinterpret_cast<const short8*>(&sm[FVT_ + d * 72 + t0]);
    }
  }
  if (tid < M_) {
    float s = 0.f;
#pragma unroll
    for (int t8 = 0; t8 < 8; ++t8) {
      const short8 h8 =
          *reinterpret_cast<const short8*>(&sm[FKPT_ + tid * 72 + t8 * 8]);
#pragma unroll
      for (int j = 0; j < 8; ++j) s += bf2f((unsigned short)h8[j]);
    }
    ksc[(size_t)(bh * C_ + c) * M_ + tid] = s;
  }
  if (tid >= 128 && tid < 128 + D_) {
    const int d = tid - 128;
    float s = 0.f;
#pragma unroll
    for (int t8 = 0; t8 < 8; ++t8) {
      const short8 h8 =
          *reinterpret_cast<const short8*>(&sm[FVT_ + d * 72 + t8 * 8]);
#pragma unroll
      for (int j = 0; j < 8; ++j) s += bf2f((unsigned short)h8[j]);
    }
    vsum[(size_t)(bh * C_ + c) * D_ + d] = s;
  }
  __syncthreads();  // s4
#pragma unroll
  for (int ti = 0; ti < 2; ++ti)
#pragma unroll
    for (int j = 0; j < 4; ++j) {
      const int row = rblk + ti * 16 + l16 * 4 + j;
#pragma unroll
      for (int tj = 0; tj < 4; ++tj) {
        const int col = cblk + tj * 16 + l15;
        sm[FKVST_ + row * 136 + col] = f2bf(acc2[ti][tj][j]);
      }
    }
  __syncthreads();  // s5
  {
    unsigned short* ob = kvc16 + (size_t)(bh * C_ + c) * (M_ * D_);
    for (int i8 = tid; i8 < D_ * 16; i8 += 256) {
      const int d = i8 >> 4, m0 = (i8 & 15) * 8;
      *reinterpret_cast<short8*>(&ob[d * M_ + m0]) =
          *reinterpret_cast<const short8*>(&sm[FKVST_ + d * 136 + m0]);
    }
  }
}

// ---------------- prefix: identical to R16 ----------------
__global__ __launch_bounds__(256) void prefix_kernel(
    const unsigned short* __restrict__ kvc16,
    unsigned short* __restrict__ kvp16, float* __restrict__ ksc,
    const float* __restrict__ blockmax, const float* __restrict__ vsum) {
  __shared__ float bm_s[C_];
  __shared__ float sc_s[C_];
  __shared__ float vs_s[2][C_];
  const int bid = blockIdx.x;  // B*H*32
  const int ej = bid & 31, bh = bid >> 5;
  if (threadIdx.x < C_) bm_s[threadIdx.x] = blockmax[bh * C_ + threadIdx.x];
  if (threadIdx.x >= 64 && threadIdx.x < 64 + 2 * C_) {
    const int t = threadIdx.x - 64;
    const int ld = t >> 5, cc = t & 31;
    vs_s[ld][cc] = vsum[(size_t)(bh * C_ + cc) * D_ + ej * 2 + ld];
  }
  __syncthreads();
  if (threadIdx.x < C_) {
    float km = -INFINITY;
#pragma unroll
    for (int cc = 0; cc < C_; ++cc) km = fmaxf(km, bm_s[cc]);
    sc_s[threadIdx.x] = expf(bm_s[threadIdx.x] - km);
  }
  __syncthreads();
  const int e = ej * 256 + threadIdx.x;
  const int dl = threadIdx.x >> 7;
  float vals[C_];
#pragma unroll
  for (int cc = 0; cc < C_; ++cc)
    vals[cc] = bf2f(kvc16[(size_t)(bh * C_ + cc) * (M_ * D_) + e]) * sc_s[cc] +
               REPS_ * vs_s[dl][cc];
  float run = 0.f;
#pragma unroll
  for (int cc = 0; cc < C_; ++cc) {
    const float t = vals[cc];
    vals[cc] = run;
    run += t;
  }
#pragma unroll
  for (int cc = 0; cc < C_; ++cc)
    kvp16[(size_t)(bh * C_ + cc) * (M_ * D_) + e] = f2bf(vals[cc]);
  if (ej == 0 && threadIdx.x < M_) {
    const int m = threadIdx.x;
    float ks[C_];
#pragma unroll
    for (int cc = 0; cc < C_; ++cc)
      ks[cc] = ksc[(size_t)(bh * C_ + cc) * M_ + m] * sc_s[cc] + KEPS_;
    float rs = 0.f;
#pragma unroll
    for (int cc = 0; cc < C_; ++cc) {
      const float t = ks[cc];
      ks[cc] = rs;
      rs += t;
    }
#pragma unroll
    for (int cc = 0; cc < C_; ++cc)
      ksc[(size_t)(bh * C_ + cc) * M_ + m] = ks[cc];
  }
}

// ---------------- intra: R16 + ONLY the S_s-aliases-KP LDS shrink ----------
// (prefetch stays at R16's post-s3 position — short register hold window;
// R18's entry-prefetch regression isolated out.)
constexpr int IXQ_ = 0, IXK_ = 4608, IPH_ = 9216;
constexpr int IQP_ = 0, IKP_ = 9216;
constexpr int IS_ = 9216;  // aliases IKP; safe: barrier between S MFMA & write

__global__ __launch_bounds__(256, 4) void intra_kernel(
    const float* __restrict__ q, const float* __restrict__ k,
    const float* __restrict__ P, const unsigned short* __restrict__ vt16,
    const unsigned short* __restrict__ kvp16, const float* __restrict__ ksp,
    const float* __restrict__ blockmax, float* __restrict__ out) {
  __shared__ __align__(16) unsigned short sm[18432];  // 36.9 KB
  __shared__ float diagq_s[T_];
  __shared__ float diagk_s[T_];
  __shared__ float wred_s[2][T_];
  __shared__ float qs2_s[2][T_];
  __shared__ float ksp_s[M_];
  __shared__ float denp_s[4][T_];
  __shared__ float den_s[T_];
  __shared__ float bm_s[C_];

  const int bid = blockIdx.x;
  const int c = bid % C_, bh = bid / C_;
  const int b = bh >> 3, h = bh & 7;
  const int tid = threadIdx.x;
  const int w = tid >> 6, lane = tid & 63;
  const int l15 = lane & 15, l16 = lane >> 4;
  const int rblk = (w >> 1) * 32;
  const int cblkF = (w & 1) * 64;
  const int cblkS = (w & 1) * 32;
  const int dblk = (w & 1) * 32;

  if (tid < C_) bm_s[tid] = blockmax[bh * C_ + tid];
  if (tid < M_) ksp_s[tid] = ksp[(size_t)(bh * C_ + c) * M_ + tid];

  // ---- stage q, k (bf16 + diag) and P ----
#pragma unroll
  for (int it = 0; it < 4; ++it) {
    const int i4 = tid + 256 * it;
    const int r = i4 >> 4, d0 = (i4 & 15) * 4;
    f32x4 t4 = *reinterpret_cast<const f32x4*>(
        &q[((size_t)(b * L_ + c * T_ + r) * H_ + h) * D_ + d0]);
    u16x4 hi;
    float sq = 0.f;
#pragma unroll
    for (int j = 0; j < 4; ++j) {
      const float xv = t4[j] * DN_;
      sq += xv * xv;
      hi[j] = f2bf(xv);
    }
    *reinterpret_cast<u16x4*>(&sm[IXQ_ + r * 72 + d0]) = hi;
#pragma unroll
    for (int off = 1; off < 16; off <<= 1) sq += __shfl_xor(sq, off, 64);
    if ((tid & 15) == 0) diagq_s[r] = sq;
  }
#pragma unroll
  for (int it = 0; it < 4; ++it) {
    const int i4 = tid + 256 * it;
    const int r = i4 >> 4, d0 = (i4 & 15) * 4;
    f32x4 t4 = *reinterpret_cast<const f32x4*>(
        &k[((size_t)(b * L_ + c * T_ + r) * H_ + h) * D_ + d0]);
    u16x4 hi;
    float sq = 0.f;
#pragma unroll
    for (int j = 0; j < 4; ++j) {
      const float xv = t4[j] * DN_;
      sq += xv * xv;
      hi[j] = f2bf(xv);
    }
    *reinterpret_cast<u16x4*>(&sm[IXK_ + r * 72 + d0]) = hi;
#pragma unroll
    for (int off = 1; off < 16; off <<= 1) sq += __shfl_xor(sq, off, 64);
    if ((tid & 15) == 0) diagk_s[r] = sq;
  }
  for (int i4 = tid; i4 < M_ * 16; i4 += 256) {
    const int m = i4 >> 4, d0 = (i4 & 15) * 4;
    const f32x4 t4 = *reinterpret_cast<const f32x4*>(&P[m * D_ + d0]);
    u16x4 hi;
#pragma unroll
    for (int j = 0; j < 4; ++j) hi[j] = f2bf(t4[j]);
    *reinterpret_cast<u16x4*>(&sm[IPH_ + m * 72 + d0]) = hi;
  }
  __syncthreads();  // s1

  // ---- dash MFMAs ----
  f32x4 accq[2][4], acck[2][4];
#pragma unroll
  for (int i = 0; i < 2; ++i)
#pragma unroll
    for (int j = 0; j < 4; ++j) {
      accq[i][j] = {0.f, 0.f, 0.f, 0.f};
      acck[i][j] = {0.f, 0.f, 0.f, 0.f};
    }
#pragma unroll
  for (int kk = 0; kk < 2; ++kk) {
    short8 aq[2], ak[2], bh8[4];
#pragma unroll
    for (int ti = 0; ti < 2; ++ti) {
      aq[ti] = *reinterpret_cast<const short8*>(
          &sm[IXQ_ + (rblk + ti * 16 + l15) * 72 + kk * 32 + l16 * 8]);
      ak[ti] = *reinterpret_cast<const short8*>(
          &sm[IXK_ + (rblk + ti * 16 + l15) * 72 + kk * 32 + l16 * 8]);
    }
#pragma unroll
    for (int tj = 0; tj < 4; ++tj)
      bh8[tj] = *reinterpret_cast<const short8*>(
          &sm[IPH_ + (cblkF + tj * 16 + l15) * 72 + kk * 32 + l16 * 8]);
#pragma unroll
    for (int ti = 0; ti < 2; ++ti)
#pragma unroll
      for (int tj = 0; tj < 4; ++tj) {
        accq[ti][tj] = __builtin_amdgcn_mfma_f32_16x16x32_bf16(
            aq[ti], bh8[tj], accq[ti][tj], 0, 0, 0);
        acck[ti][tj] = __builtin_amdgcn_mfma_f32_16x16x32_bf16(
            ak[ti], bh8[tj], acck[ti][tj], 0, 0, 0);
      }
  }
  {  // Q per-row max
    float rmax[2][4];
#pragma unroll
    for (int ti = 0; ti < 2; ++ti)
#pragma unroll
      for (int j = 0; j < 4; ++j) {
        float m0 = fmaxf(fmaxf(accq[ti][0][j], accq[ti][1][j]),
                         fmaxf(accq[ti][2][j], accq[ti][3][j]));
#pragma unroll
        for (int off = 1; off < 16; off <<= 1)
          m0 = fmaxf(m0, __shfl_xor(m0, off, 64));
        rmax[ti][j] = m0;
      }
    if (l15 == 0) {
#pragma unroll
      for (int ti = 0; ti < 2; ++ti)
#pragma unroll
        for (int j = 0; j < 4; ++j)
          wred_s[w & 1][rblk + ti * 16 + l16 * 4 + j] = rmax[ti][j];
    }
  }
  __syncthreads();  // s2: wred visible; dash reads of XQ/XK/PH done

  const float lmax = bm_s[c];  // same units as feat's kpE
  // ---- epilogues: qp -> QP + qsum halves; kpE -> KP (over PH) ----
#pragma unroll
  for (int ti = 0; ti < 2; ++ti)
#pragma unroll
    for (int j = 0; j < 4; ++j) {
      const int row = rblk + ti * 16 + l16 * 4 + j;
      const float subq =
          0.5f * diagq_s[row] + fmaxf(wred_s[0][row], wred_s[1][row]);
      const float subk = 0.5f * diagk_s[row] + lmax;
      float qsp = 0.f;
#pragma unroll
      for (int tj = 0; tj < 4; ++tj) {
        const int col = cblkF + tj * 16 + l15;
        const float qv = RATIO_ * (expf(accq[ti][tj][j] - subq) + EPSV_);
        qsp += qv;
        sm[IQP_ + row * 136 + col] = f2bf(qv);
        sm[IKP_ + row * 136 + col] =
            f2bf(RATIO_ * expf(acck[ti][tj][j] - subk));
      }
#pragma unroll
      for (int off = 1; off < 16; off <<= 1) qsp += __shfl_xor(qsp, off, 64);
      if (l15 == 0) qs2_s[w & 1][row] = qsp;
    }
  __syncthreads();  // s3: QP/KP/qs2 visible

  // ---- T14 prefetch PV B-frags (R16 placement: short hold window) ----
  const unsigned short* kvt = kvp16 + (size_t)(bh * C_ + c) * (M_ * D_);
  const unsigned short* vg = vt16 + (size_t)(bh * C_ + c) * (D_ * T_);
  short8 vtr[2][2], kvr[4][2];
#pragma unroll
  for (int kk = 0; kk < 2; ++kk)
#pragma unroll
    for (int tj = 0; tj < 2; ++tj)
      vtr[kk][tj] = *reinterpret_cast<const short8*>(
          &vg[(dblk + tj * 16 + l15) * T_ + kk * 32 + l16 * 8]);
#pragma unroll
  for (int kk = 0; kk < 4; ++kk)
#pragma unroll
    for (int tj = 0; tj < 2; ++tj)
      kvr[kk][tj] = *reinterpret_cast<const short8*>(
          &kvt[(dblk + tj * 16 + l15) * M_ + kk * 32 + l16 * 8]);

  float km = -INFINITY;
#pragma unroll
  for (int cc = 0; cc < C_; ++cc) km = fmaxf(km, bm_s[cc]);
  const float sc = expf(bm_s[c] - km);

  // ---- S MFMA (reads QP + KP) ----
  f32x4 Sacc[2][2];
#pragma unroll
  for (int i = 0; i < 2; ++i)
#pragma unroll
    for (int j = 0; j < 2; ++j) Sacc[i][j] = {0.f, 0.f, 0.f, 0.f};
#pragma unroll
  for (int kk = 0; kk < 4; ++kk) {
    short8 af[2], bf[2];
#pragma unroll
    for (int ti = 0; ti < 2; ++ti)
      af[ti] = *reinterpret_cast<const short8*>(
          &sm[IQP_ + (rblk + ti * 16 + l15) * 136 + kk * 32 + l16 * 8]);
#pragma unroll
    for (int tj = 0; tj < 2; ++tj)
      bf[tj] = *reinterpret_cast<const short8*>(
          &sm[IKP_ + (cblkS + tj * 16 + l15) * 136 + kk * 32 + l16 * 8]);
#pragma unroll
    for (int ti = 0; ti < 2; ++ti)
#pragma unroll
      for (int tj = 0; tj < 2; ++tj)
        Sacc[ti][tj] = __builtin_amdgcn_mfma_f32_16x16x32_bf16(
            af[ti], bf[tj], Sacc[ti][tj], 0, 0, 0);
  }
  __syncthreads();  // s3b: ALL waves' KP reads done -> S_s may alias KP

#pragma unroll
  for (int ti = 0; ti < 2; ++ti)
#pragma unroll
    for (int tj = 0; tj < 2; ++tj)
#pragma unroll
      for (int j = 0; j < 4; ++j) {
        const int row = rblk + ti * 16 + l16 * 4 + j;
        const int col = cblkS + tj * 16 + l15;
        const float add = REPS_ * (qs2_s[0][row] + qs2_s[1][row]);
        const float sv = (col <= row) ? Sacc[ti][tj][j] * sc + add : 0.f;
        sm[IS_ + row * 72 + col] = f2bf(sv);
      }
  __syncthreads();  // s4: S_s visible

  {  // den partials
    const int t = lane;
    float p = 0.f;
    if (w == 0) {
      for (int tp = 0; tp < 32; ++tp) p += bf2f(sm[IS_ + t * 72 + tp]);
    } else if (w == 1) {
      for (int tp = 32; tp < 64; ++tp) p += bf2f(sm[IS_ + t * 72 + tp]);
    } else if (w == 2) {
      for (int m = 0; m < 64; ++m)
        p += bf2f(sm[IQP_ + t * 136 + m]) * ksp_s[m];
    } else {
      for (int m = 64; m < 128; ++m)
        p += bf2f(sm[IQP_ + t * 136 + m]) * ksp_s[m];
    }
    denp_s[w][t] = p;
  }
  __syncthreads();  // s5
  if (tid < T_)
    den_s[tid] =
        denp_s[0][tid] + denp_s[1][tid] + denp_s[2][tid] + denp_s[3][tid];
  __syncthreads();  // s6

  // ---- PV: num = S@V^T + qp@KVp^T ----
  f32x4 Nacc[2][2];
#pragma unroll
  for (int i = 0; i < 2; ++i)
#pragma unroll
    for (int j = 0; j < 2; ++j) Nacc[i][j] = {0.f, 0.f, 0.f, 0.f};
#pragma unroll
  for (int kk = 0; kk < 2; ++kk) {
    short8 af[2];
#pragma unroll
    for (int ti = 0; ti < 2; ++ti)
      af[ti] = *reinterpret_cast<const short8*>(
          &sm[IS_ + (rblk + ti * 16 + l15) * 72 + kk * 32 + l16 * 8]);
#pragma unroll
    for (int ti = 0; ti < 2; ++ti)
#pragma unroll
      for (int tj = 0; tj < 2; ++tj)
        Nacc[ti][tj] = __builtin_amdgcn_mfma_f32_16x16x32_bf16(
            af[ti], vtr[kk][tj], Nacc[ti][tj], 0, 0, 0);
  }
#pragma unroll
  for (int kk = 0; kk < 4; ++kk) {
    short8 af[2];
#pragma unroll
    for (int ti = 0; ti < 2; ++ti)
      af[ti] = *reinterpret_cast<const short8*>(
          &sm[IQP_ + (rblk + ti * 16 + l15) * 136 + kk * 32 + l16 * 8]);
#pragma unroll
    for (int ti = 0; ti < 2; ++ti)
#pragma unroll
      for (int tj = 0; tj < 2; ++tj)
        Nacc[ti][tj] = __builtin_amdgcn_mfma_f32_16x16x32_bf16(
            af[ti], kvr[kk][tj], Nacc[ti][tj], 0, 0, 0);
  }

#pragma unroll
  for (int ti = 0; ti < 2; ++ti)
#pragma unroll
    for (int j = 0; j < 4; ++j) {
      const int row = rblk + ti * 16 + l16 * 4 + j;
      const float r = 1.f / den_s[row];
      float* orow = out + ((size_t)(b * L_ + c * T_ + row) * H_ + h) * D_;
#pragma unroll
      for (int tj = 0; tj < 2; ++tj) {
        const int col = dblk + tj * 16 + l15;
        orow[col] = Nacc[ti][tj][j] * r;
      }
    }
}

extern "C" void kernel_launch(void* const* d_in, const int* in_sizes, int n_in,
                              void* d_out, int out_size, void* d_ws,
                              size_t ws_size, hipStream_t stream) {
  const float* q = (const float*)d_in[0];
  const float* k = (const float*)d_in[1];
  const float* v = (const float*)d_in[2];
  const float* P = (const float*)d_in[3];
  float* out = (float*)d_out;

  // Workspace (~26 MB): blockmax | ksc | vsum | kvc16 | kvp16 | vt16
  float* ws = (float*)d_ws;
  float* blockmax = ws;                                   // 512
  float* ksc = blockmax + 512;                            // B*H*C*M
  float* vsum = ksc + (size_t)B_ * H_ * C_ * M_;          // B*H*C*D
  unsigned short* kvc16 = (unsigned short*)(vsum + (size_t)B_ * H_ * C_ * D_);
  unsigned short* kvp16 = kvc16 + (size_t)B_ * H_ * C_ * D_ * M_;
  unsigned short* vt16 = kvp16 + (size_t)B_ * H_ * C_ * D_ * M_;

  feat_kernel<<<B_ * H_ * C_, 256, 0, stream>>>(k, P, v, kvc16, ksc, vt16,
                                                blockmax, vsum);
  prefix_kernel<<<B_ * H_ * 32, 256, 0, stream>>>(kvc16, kvp16, ksc, blockmax,
                                                  vsum);
  intra_kernel<<<B_ * H_ * C_, 256, 0, stream>>>(q, k, P, vt16, kvp16, ksc,
                                                 blockmax, out);
}